// Round 1
// baseline (1636.846 us; speedup 1.0000x reference)
//
#include <hip/hip_runtime.h>
#include <cstddef>

#define BATCH 131072
#define ROWS 64

__device__ __forceinline__ float fsigmoid(float x) {
    return __builtin_amdgcn_rcpf(1.0f + __expf(-x));
}
__device__ __forceinline__ float ftanh(float x) {
    // tanh(x) = 1 - 2/(exp(2x)+1); saturates correctly at +-1
    return 1.0f - 2.0f * __builtin_amdgcn_rcpf(1.0f + __expf(2.0f * x));
}

extern "C" __global__ __launch_bounds__(256, 1)
void gru_wm(const float* __restrict__ z_t,
            const int*   __restrict__ action,
            const float* __restrict__ hidden,
            const float* __restrict__ embed,
            const float* __restrict__ fuse_W, const float* __restrict__ fuse_b,
            const float* __restrict__ W_ih,   const float* __restrict__ W_hh,
            const float* __restrict__ b_ih,   const float* __restrict__ b_hh,
            const float* __restrict__ ns_W1,  const float* __restrict__ ns_b1,
            const float* __restrict__ ns_W2,  const float* __restrict__ ns_b2,
            const float* __restrict__ rw_W1,  const float* __restrict__ rw_b1,
            const float* __restrict__ rw_W2,  const float* __restrict__ rw_b2,
            const float* __restrict__ dn_W1,  const float* __restrict__ dn_b1,
            const float* __restrict__ dn_W2,  const float* __restrict__ dn_b2,
            float* __restrict__ out)
{
    // Transposed activation tiles: [feature][row], stride 65 (odd) -> 2-way LDS bank access (free)
    __shared__ float sF[80][65];    // fused input; later: z_next staging (rows 0..63)
    __shared__ float sX[128][65];   // x = relu(fuse); later: t1 (ns hidden)
    __shared__ float sH0[128][65];  // h0; later: t2_rw (rows 0..63), t2_dn (rows 64..127)
    __shared__ float sHN[128][65];  // h_new (persists to the end)

    const int t    = threadIdx.x;
    const int lane = t & 63;
    const int wid  = __builtin_amdgcn_readfirstlane(t >> 6);  // wave id 0..3 (scalar)
    const int row0 = blockIdx.x * ROWS;

    // ---------------- stage inputs (coalesced global -> transposed LDS) ----------------
    #pragma unroll
    for (int p = 0; p < 16; ++p) {                 // z_t: 64 rows x 64
        int idx = p * 256 + t;
        int r = idx >> 6, c = idx & 63;
        sF[c][r] = z_t[(size_t)(row0 + r) * 64 + c];
    }
    #pragma unroll
    for (int p = 0; p < 4; ++p) {                  // a_emb: 64 rows x 16
        int idx = p * 256 + t;
        int r = idx >> 4, d = idx & 15;
        int a = action[row0 + r];
        sF[64 + d][r] = embed[a * 16 + d];
    }
    #pragma unroll
    for (int p = 0; p < 32; ++p) {                 // h0: 64 rows x 128
        int idx = p * 256 + t;
        int r = idx >> 7, c = idx & 127;
        sH0[c][r] = hidden[(size_t)(row0 + r) * 128 + c];
    }
    __syncthreads();

    // ---------------- fuse: x = relu(F @ fuse_W^T + fuse_b), j split across waves ----------------
    #pragma unroll 1
    for (int jb = 0; jb < 32; jb += 4) {
        const int j0 = wid * 32 + jb;
        const float* w0 = fuse_W + (size_t)(j0 + 0) * 80;
        const float* w1 = fuse_W + (size_t)(j0 + 1) * 80;
        const float* w2 = fuse_W + (size_t)(j0 + 2) * 80;
        const float* w3 = fuse_W + (size_t)(j0 + 3) * 80;
        float a0 = fuse_b[j0+0], a1 = fuse_b[j0+1], a2 = fuse_b[j0+2], a3 = fuse_b[j0+3];
        #pragma unroll 4
        for (int k = 0; k < 80; ++k) {
            float v = sF[k][lane];
            a0 = fmaf(w0[k], v, a0);
            a1 = fmaf(w1[k], v, a1);
            a2 = fmaf(w2[k], v, a2);
            a3 = fmaf(w3[k], v, a3);
        }
        sX[j0+0][lane] = fmaxf(a0, 0.0f);
        sX[j0+1][lane] = fmaxf(a1, 0.0f);
        sX[j0+2][lane] = fmaxf(a2, 0.0f);
        sX[j0+3][lane] = fmaxf(a3, 0.0f);
    }
    __syncthreads();

    // ---------------- GRU cell: 6 dot streams per j (2 j's at a time = 12 FMA / 2 LDS reads) ----------------
    #pragma unroll 1
    for (int jb = 0; jb < 32; jb += 2) {
        const int j0 = wid * 32 + jb;
        const float* wir0 = W_ih + (size_t)(      j0    ) * 128;
        const float* wir1 = W_ih + (size_t)(      j0 + 1) * 128;
        const float* wiz0 = W_ih + (size_t)(128 + j0    ) * 128;
        const float* wiz1 = W_ih + (size_t)(128 + j0 + 1) * 128;
        const float* win0 = W_ih + (size_t)(256 + j0    ) * 128;
        const float* win1 = W_ih + (size_t)(256 + j0 + 1) * 128;
        const float* whr0 = W_hh + (size_t)(      j0    ) * 128;
        const float* whr1 = W_hh + (size_t)(      j0 + 1) * 128;
        const float* whz0 = W_hh + (size_t)(128 + j0    ) * 128;
        const float* whz1 = W_hh + (size_t)(128 + j0 + 1) * 128;
        const float* whn0 = W_hh + (size_t)(256 + j0    ) * 128;
        const float* whn1 = W_hh + (size_t)(256 + j0 + 1) * 128;

        float air0 = b_ih[j0],       air1 = b_ih[j0+1];
        float aiz0 = b_ih[128+j0],   aiz1 = b_ih[128+j0+1];
        float ain0 = b_ih[256+j0],   ain1 = b_ih[256+j0+1];
        float ahr0 = b_hh[j0],       ahr1 = b_hh[j0+1];
        float ahz0 = b_hh[128+j0],   ahz1 = b_hh[128+j0+1];
        float ahn0 = b_hh[256+j0],   ahn1 = b_hh[256+j0+1];

        #pragma unroll 4
        for (int k = 0; k < 128; ++k) {
            float xv = sX[k][lane];
            float hv = sH0[k][lane];
            air0 = fmaf(wir0[k], xv, air0);  air1 = fmaf(wir1[k], xv, air1);
            aiz0 = fmaf(wiz0[k], xv, aiz0);  aiz1 = fmaf(wiz1[k], xv, aiz1);
            ain0 = fmaf(win0[k], xv, ain0);  ain1 = fmaf(win1[k], xv, ain1);
            ahr0 = fmaf(whr0[k], hv, ahr0);  ahr1 = fmaf(whr1[k], hv, ahr1);
            ahz0 = fmaf(whz0[k], hv, ahz0);  ahz1 = fmaf(whz1[k], hv, ahz1);
            ahn0 = fmaf(whn0[k], hv, ahn0);  ahn1 = fmaf(whn1[k], hv, ahn1);
        }
        {
            float r  = fsigmoid(air0 + ahr0);
            float zg = fsigmoid(aiz0 + ahz0);
            float n  = ftanh(ain0 + r * ahn0);
            float h0v = sH0[j0][lane];
            sHN[j0][lane] = (1.0f - zg) * n + zg * h0v;
        }
        {
            float r  = fsigmoid(air1 + ahr1);
            float zg = fsigmoid(aiz1 + ahz1);
            float n  = ftanh(ain1 + r * ahn1);
            float h0v = sH0[j0+1][lane];
            sHN[j0+1][lane] = (1.0f - zg) * n + zg * h0v;
        }
    }
    __syncthreads();

    // ---------------- head hidden layers: t1 (ns) -> sX, t2_rw -> sH0[0..63], t2_dn -> sH0[64..127] ----------------
    #pragma unroll 1
    for (int jb = 0; jb < 32; jb += 4) {
        const int j0 = wid * 32 + jb;
        const float* w0 = ns_W1 + (size_t)(j0 + 0) * 128;
        const float* w1 = ns_W1 + (size_t)(j0 + 1) * 128;
        const float* w2 = ns_W1 + (size_t)(j0 + 2) * 128;
        const float* w3 = ns_W1 + (size_t)(j0 + 3) * 128;
        float a0 = ns_b1[j0+0], a1 = ns_b1[j0+1], a2 = ns_b1[j0+2], a3 = ns_b1[j0+3];
        #pragma unroll 4
        for (int k = 0; k < 128; ++k) {
            float v = sHN[k][lane];
            a0 = fmaf(w0[k], v, a0);
            a1 = fmaf(w1[k], v, a1);
            a2 = fmaf(w2[k], v, a2);
            a3 = fmaf(w3[k], v, a3);
        }
        sX[j0+0][lane] = fmaxf(a0, 0.0f);
        sX[j0+1][lane] = fmaxf(a1, 0.0f);
        sX[j0+2][lane] = fmaxf(a2, 0.0f);
        sX[j0+3][lane] = fmaxf(a3, 0.0f);
    }
    #pragma unroll 1
    for (int jb = 0; jb < 16; jb += 4) {
        const int j0 = wid * 16 + jb;
        const float* w0 = rw_W1 + (size_t)(j0 + 0) * 128;
        const float* w1 = rw_W1 + (size_t)(j0 + 1) * 128;
        const float* w2 = rw_W1 + (size_t)(j0 + 2) * 128;
        const float* w3 = rw_W1 + (size_t)(j0 + 3) * 128;
        const float* v0 = dn_W1 + (size_t)(j0 + 0) * 128;
        const float* v1 = dn_W1 + (size_t)(j0 + 1) * 128;
        const float* v2 = dn_W1 + (size_t)(j0 + 2) * 128;
        const float* v3 = dn_W1 + (size_t)(j0 + 3) * 128;
        float a0 = rw_b1[j0+0], a1 = rw_b1[j0+1], a2 = rw_b1[j0+2], a3 = rw_b1[j0+3];
        float b0 = dn_b1[j0+0], b1 = dn_b1[j0+1], b2 = dn_b1[j0+2], b3 = dn_b1[j0+3];
        #pragma unroll 4
        for (int k = 0; k < 128; ++k) {
            float v = sHN[k][lane];
            a0 = fmaf(w0[k], v, a0);
            a1 = fmaf(w1[k], v, a1);
            a2 = fmaf(w2[k], v, a2);
            a3 = fmaf(w3[k], v, a3);
            b0 = fmaf(v0[k], v, b0);
            b1 = fmaf(v1[k], v, b1);
            b2 = fmaf(v2[k], v, b2);
            b3 = fmaf(v3[k], v, b3);
        }
        sH0[j0+0][lane] = fmaxf(a0, 0.0f);
        sH0[j0+1][lane] = fmaxf(a1, 0.0f);
        sH0[j0+2][lane] = fmaxf(a2, 0.0f);
        sH0[j0+3][lane] = fmaxf(a3, 0.0f);
        sH0[64+j0+0][lane] = fmaxf(b0, 0.0f);
        sH0[64+j0+1][lane] = fmaxf(b1, 0.0f);
        sH0[64+j0+2][lane] = fmaxf(b2, 0.0f);
        sH0[64+j0+3][lane] = fmaxf(b3, 0.0f);
    }
    __syncthreads();

    // ---------------- output layers ----------------
    // z_next -> stage into sF rows 0..63
    #pragma unroll 1
    for (int ib = 0; ib < 16; ib += 4) {
        const int i0 = wid * 16 + ib;
        const float* w0 = ns_W2 + (size_t)(i0 + 0) * 128;
        const float* w1 = ns_W2 + (size_t)(i0 + 1) * 128;
        const float* w2 = ns_W2 + (size_t)(i0 + 2) * 128;
        const float* w3 = ns_W2 + (size_t)(i0 + 3) * 128;
        float a0 = ns_b2[i0+0], a1 = ns_b2[i0+1], a2 = ns_b2[i0+2], a3 = ns_b2[i0+3];
        #pragma unroll 4
        for (int k = 0; k < 128; ++k) {
            float v = sX[k][lane];
            a0 = fmaf(w0[k], v, a0);
            a1 = fmaf(w1[k], v, a1);
            a2 = fmaf(w2[k], v, a2);
            a3 = fmaf(w3[k], v, a3);
        }
        sF[i0+0][lane] = a0;
        sF[i0+1][lane] = a1;
        sF[i0+2][lane] = a2;
        sF[i0+3][lane] = a3;
    }
    // reward (wave 0) / done (wave 1): single dot K=64, coalesced store (lane = row)
    if (wid == 0) {
        float acc = rw_b2[0];
        #pragma unroll 4
        for (int k = 0; k < 64; ++k) acc = fmaf(rw_W2[k], sH0[k][lane], acc);
        out[(size_t)BATCH * 64 + row0 + lane] = acc;
    } else if (wid == 1) {
        float acc = dn_b2[0];
        #pragma unroll 4
        for (int k = 0; k < 64; ++k) acc = fmaf(dn_W2[k], sH0[64 + k][lane], acc);
        out[(size_t)BATCH * 65 + row0 + lane] = acc;
    }
    __syncthreads();

    // ---------------- coalesced stores of z_next and h_new ----------------
    #pragma unroll
    for (int p = 0; p < 16; ++p) {
        int idx = p * 256 + t;
        int r = idx >> 6, i = idx & 63;
        out[(size_t)(row0 + r) * 64 + i] = sF[i][r];
    }
    #pragma unroll
    for (int p = 0; p < 32; ++p) {
        int idx = p * 256 + t;
        int r = idx >> 7, c = idx & 127;
        out[(size_t)BATCH * 66 + (size_t)(row0 + r) * 128 + c] = sHN[c][r];
    }
}

extern "C" void kernel_launch(void* const* d_in, const int* in_sizes, int n_in,
                              void* d_out, int out_size, void* d_ws, size_t ws_size,
                              hipStream_t stream) {
    const float* z_t    = (const float*)d_in[0];
    const int*   action = (const int*)  d_in[1];
    const float* hidden = (const float*)d_in[2];
    const float* embed  = (const float*)d_in[3];
    const float* fuse_W = (const float*)d_in[4];
    const float* fuse_b = (const float*)d_in[5];
    const float* W_ih   = (const float*)d_in[6];
    const float* W_hh   = (const float*)d_in[7];
    const float* b_ih   = (const float*)d_in[8];
    const float* b_hh   = (const float*)d_in[9];
    const float* ns_W1  = (const float*)d_in[10];
    const float* ns_b1  = (const float*)d_in[11];
    const float* ns_W2  = (const float*)d_in[12];
    const float* ns_b2  = (const float*)d_in[13];
    const float* rw_W1  = (const float*)d_in[14];
    const float* rw_b1  = (const float*)d_in[15];
    const float* rw_W2  = (const float*)d_in[16];
    const float* rw_b2  = (const float*)d_in[17];
    const float* dn_W1  = (const float*)d_in[18];
    const float* dn_b1  = (const float*)d_in[19];
    const float* dn_W2  = (const float*)d_in[20];
    const float* dn_b2  = (const float*)d_in[21];
    float* out = (float*)d_out;

    dim3 grid(BATCH / ROWS), block(256);
    hipLaunchKernelGGL(gru_wm, grid, block, 0, stream,
                       z_t, action, hidden, embed,
                       fuse_W, fuse_b, W_ih, W_hh, b_ih, b_hh,
                       ns_W1, ns_b1, ns_W2, ns_b2,
                       rw_W1, rw_b1, rw_W2, rw_b2,
                       dn_W1, dn_b1, dn_W2, dn_b2,
                       out);
}

// Round 2
// 255.252 us; speedup vs baseline: 6.4127x; 6.4127x over previous
//
#include <hip/hip_runtime.h>
#include <cstddef>
#include <cstdint>

#define BATCH 131072
#define HOFF ((size_t)BATCH * 66)

typedef __attribute__((ext_vector_type(8))) short short8;
typedef __attribute__((ext_vector_type(4))) short short4v;
typedef __attribute__((ext_vector_type(4))) float f32x4;

// d_ws layout (bf16 elems): fuse [128][104] | 16 GRU units (48 rows x 136, padded to 6656)
//                           | 10 head units (32 rows x 136, padded to 4608)
#define WS_WF    0
#define WS_GRU   13312
#define WS_HEAD  119808
#define WS_ELEMS 165888

#define MFMA(a,b,c) __builtin_amdgcn_mfma_f32_16x16x32_bf16((a),(b),(c),0,0,0)

__device__ __forceinline__ short f2bf(float x) {
    unsigned u = __builtin_bit_cast(unsigned, x);
    unsigned r = (u + 0x7fffu + ((u >> 16) & 1u)) >> 16;   // RNE
    return (short)r;
}
__device__ __forceinline__ float bf2f(short s) {
    unsigned u = ((unsigned)(unsigned short)s) << 16;
    return __builtin_bit_cast(float, u);
}
__device__ __forceinline__ float fsigmoid(float x) { return __builtin_amdgcn_rcpf(1.0f + __expf(-x)); }
__device__ __forceinline__ float ftanh(float x)    { return 1.0f - 2.0f * __builtin_amdgcn_rcpf(1.0f + __expf(2.0f * x)); }

__device__ __forceinline__ short8 packbf(f32x4 a, f32x4 b) {
    short8 r;
    r[0]=f2bf(a[0]); r[1]=f2bf(a[1]); r[2]=f2bf(a[2]); r[3]=f2bf(a[3]);
    r[4]=f2bf(b[0]); r[5]=f2bf(b[1]); r[6]=f2bf(b[2]); r[7]=f2bf(b[3]);
    return r;
}

__device__ __forceinline__ void stage_issue(const short* __restrict__ src, int nch, int t, short8 st[4]) {
    #pragma unroll
    for (int k = 0; k < 4; ++k) { int c = t + 256*k; if (c < nch) st[k] = *(const short8*)(src + c*8); }
}
__device__ __forceinline__ void stage_commit(short* dst, int nch, int t, const short8 st[4]) {
    #pragma unroll
    for (int k = 0; k < 4; ++k) { int c = t + 256*k; if (c < nch) *(short8*)(dst + c*8) = st[k]; }
}

// ---------------- prep: f32 weights -> bf16 units in d_ws ----------------
extern "C" __global__ void prep_weights(const float* __restrict__ fuse_W,
                                        const float* __restrict__ W_ih, const float* __restrict__ W_hh,
                                        const float* __restrict__ ns_W1, const float* __restrict__ ns_W2,
                                        const float* __restrict__ rw_W1, const float* __restrict__ dn_W1,
                                        short* __restrict__ ws) {
    int i = blockIdx.x * 256 + threadIdx.x;
    if (i >= WS_ELEMS) return;
    float v = 0.f;
    if (i < WS_GRU) {                       // fuse: [128][104], K padded 80->104
        int j = i / 104, k = i % 104;
        if (k < 80) v = fuse_W[j*80 + k];
    } else if (i < WS_HEAD) {               // GRU units: j = u>>1, part = u&1 (ih/hh), rows gate*16+rr
        int g = (i - WS_GRU) / 6656, e = (i - WS_GRU) % 6656;
        int r = e / 136, k = e % 136;
        if (r < 48 && k < 128) {
            int j = g >> 1;
            const float* W = (g & 1) ? W_hh : W_ih;
            int gate = r >> 4, rr = r & 15;
            v = W[(size_t)(gate*128 + j*16 + rr)*128 + k];
        }
    } else {                                // head units: 0-3 ns_W1, 4-5 ns_W2, 6-7 rw_W1, 8-9 dn_W1
        int h = (i - WS_HEAD) / 4608, e = (i - WS_HEAD) % 4608;
        int r = e / 136, k = e % 136;
        if (r < 32 && k < 128) {
            const float* W; int rb;
            if (h < 4)      { W = ns_W1; rb = h*32; }
            else if (h < 6) { W = ns_W2; rb = (h-4)*32; }
            else if (h < 8) { W = rw_W1; rb = (h-6)*32; }
            else            { W = dn_W1; rb = (h-8)*32; }
            v = W[(size_t)(rb + r)*128 + k];
        }
    }
    ws[i] = f2bf(v);
}

// ---------------- main fused kernel ----------------
extern "C" __global__ __launch_bounds__(256, 2)
void gru_mfma(const float* __restrict__ z_t, const int* __restrict__ action,
              const float* __restrict__ hidden, const float* __restrict__ embed,
              const float* __restrict__ fuse_b,
              const float* __restrict__ b_ih, const float* __restrict__ b_hh,
              const float* __restrict__ ns_b1, const float* __restrict__ ns_b2,
              const float* __restrict__ rw_b1, const float* __restrict__ rw_W2, const float* __restrict__ rw_b2,
              const float* __restrict__ dn_b1, const float* __restrict__ dn_W2, const float* __restrict__ dn_b2,
              const short* __restrict__ ws, float* __restrict__ out)
{
    // [0,13312): weight double-buffer (2 x 6656 shorts). [13312,30720): 4 x 4352 per-wave act buffers.
    __shared__ __align__(16) short smem[30720];   // 61440 B -> 2 blocks/CU

    const int t    = threadIdx.x;
    const int lane = t & 63;
    const int w    = t >> 6;
    const int lo   = lane & 15;
    const int hi   = lane >> 4;
    const int R    = blockIdx.x * 128 + w * 32;   // wave's first batch row
    short* const aw = &smem[13312 + w * 4352];    // act buffer, row stride 136 shorts (272 B, odd 16B count)

    const f32x4 zz4 = {0.f, 0.f, 0.f, 0.f};

    // ---- A-fragments direct from global (row-major == A layout), f32 -> bf16 ----
    short8 fa[2][3];   // fused input, K=96 (z_t 0..63 | emb 64..79 | zero 80..95)
    short8 ha[2][4];   // h0, K=128
    #pragma unroll
    for (int rt = 0; rt < 2; ++rt) {
        const int row = R + rt*16 + lo;
        #pragma unroll
        for (int kt = 0; kt < 2; ++kt) {
            f32x4 p0 = *(const f32x4*)&z_t[(size_t)row*64 + kt*32 + hi*8];
            f32x4 p1 = *(const f32x4*)&z_t[(size_t)row*64 + kt*32 + hi*8 + 4];
            fa[rt][kt] = packbf(p0, p1);
        }
        if (hi < 2) {
            int a = action[row];
            f32x4 e0 = *(const f32x4*)&embed[a*16 + hi*8];
            f32x4 e1 = *(const f32x4*)&embed[a*16 + hi*8 + 4];
            fa[rt][2] = packbf(e0, e1);
        } else {
            short8 z8 = {0,0,0,0,0,0,0,0};
            fa[rt][2] = z8;
        }
        #pragma unroll
        for (int kt = 0; kt < 4; ++kt) {
            f32x4 p0 = *(const f32x4*)&hidden[(size_t)row*128 + kt*32 + hi*8];
            f32x4 p1 = *(const f32x4*)&hidden[(size_t)row*128 + kt*32 + hi*8 + 4];
            ha[rt][kt] = packbf(p0, p1);
        }
    }

    // ---- stage fuse weights (whole 26624 B buffer) ----
    #pragma unroll
    for (int k = 0; k < 7; ++k) {
        int c = t + 256*k;
        if (c < 1664) *(short8*)(&smem[c*8]) = *(const short8*)(ws + c*8);
    }
    __syncthreads();

    short8 st[4];
    stage_issue(ws + WS_GRU, 832, t, st);         // prefetch GRU unit 0 (T14 split)

    // ---- fuse: x = relu(F @ fuse_W^T + b) ----
    #pragma unroll 1
    for (int ct = 0; ct < 8; ++ct) {
        float fb = fuse_b[ct*16 + lo];
        f32x4 a0 = zz4, a1 = zz4;
        #pragma unroll
        for (int kt = 0; kt < 3; ++kt) {
            short8 B = *(const short8*)&smem[(ct*16 + lo)*104 + kt*32 + hi*8];
            a0 = MFMA(fa[0][kt], B, a0);
            a1 = MFMA(fa[1][kt], B, a1);
        }
        #pragma unroll
        for (int e = 0; e < 4; ++e) {
            aw[(4*hi + e)*136 + ct*16 + lo]        = f2bf(fmaxf(a0[e] + fb, 0.f));
            aw[(16 + 4*hi + e)*136 + ct*16 + lo]   = f2bf(fmaxf(a1[e] + fb, 0.f));
        }
    }
    // x A-frags (own wave's LDS; compiler orders via lgkmcnt)
    short8 xa[2][4];
    #pragma unroll
    for (int rt = 0; rt < 2; ++rt)
        #pragma unroll
        for (int kt = 0; kt < 4; ++kt)
            xa[rt][kt] = *(const short8*)&aw[(rt*16 + lo)*136 + kt*32 + hi*8];

    __syncthreads();                               // everyone done with fuse weights
    stage_commit(&smem[0], 832, t, st);            // publish GRU unit 0 -> half 0
    __syncthreads();

    // ---- unit pipeline: 0..15 GRU (even=gi, odd=gh+elementwise), 16..19 ns1, 20..21 ns2, 22..23 rw1, 24..25 dn1 ----
    f32x4 accI[3][2], accH[3][2];
    short8 hfa[2][4], ta[2][4];

    #pragma unroll 1
    for (int u = 0; u < 26; ++u) {
        if (u < 25) {
            const int un = u + 1;
            const short* src = (un < 16) ? (ws + WS_GRU + un*6656) : (ws + WS_HEAD + (un-16)*4608);
            const int nch = (un < 16) ? 832 : 576;
            stage_issue(src, nch, t, st);
        }
        const int halfB = (u & 1) * 6656;

        if (u < 16) {
            if ((u & 1) == 0) {                    // gi = x @ W_ih^T  (3 gate row-groups)
                #pragma unroll
                for (int g = 0; g < 3; ++g) {
                    accI[g][0] = zz4; accI[g][1] = zz4;
                    #pragma unroll
                    for (int kt = 0; kt < 4; ++kt) {
                        short8 B = *(const short8*)&smem[halfB + (g*16 + lo)*136 + kt*32 + hi*8];
                        accI[g][0] = MFMA(xa[0][kt], B, accI[g][0]);
                        accI[g][1] = MFMA(xa[1][kt], B, accI[g][1]);
                    }
                }
            } else {                               // gh = h0 @ W_hh^T, then GRU elementwise
                const int j0 = (u >> 1) * 16;
                float h0v[2][4];
                #pragma unroll
                for (int rt = 0; rt < 2; ++rt)
                    #pragma unroll
                    for (int e = 0; e < 4; ++e)
                        h0v[rt][e] = hidden[(size_t)(R + rt*16 + 4*hi + e)*128 + j0 + lo];
                #pragma unroll
                for (int g = 0; g < 3; ++g) {
                    accH[g][0] = zz4; accH[g][1] = zz4;
                    #pragma unroll
                    for (int kt = 0; kt < 4; ++kt) {
                        short8 B = *(const short8*)&smem[halfB + (g*16 + lo)*136 + kt*32 + hi*8];
                        accH[g][0] = MFMA(ha[0][kt], B, accH[g][0]);
                        accH[g][1] = MFMA(ha[1][kt], B, accH[g][1]);
                    }
                }
                const float bir = b_ih[j0+lo], biz = b_ih[128+j0+lo], bin = b_ih[256+j0+lo];
                const float bhr = b_hh[j0+lo], bhz = b_hh[128+j0+lo], bhn = b_hh[256+j0+lo];
                #pragma unroll
                for (int rt = 0; rt < 2; ++rt) {
                    #pragma unroll
                    for (int e = 0; e < 4; ++e) {
                        float rg = fsigmoid(accI[0][rt][e] + bir + accH[0][rt][e] + bhr);
                        float zg = fsigmoid(accI[1][rt][e] + biz + accH[1][rt][e] + bhz);
                        float ng = ftanh(accI[2][rt][e] + bin + rg*(accH[2][rt][e] + bhn));
                        float hn = (1.f - zg)*ng + zg*h0v[rt][e];
                        aw[(rt*16 + 4*hi + e)*136 + j0 + lo] = f2bf(hn);
                    }
                }
            }
        } else {
            if (u == 16) {                         // h_new: coalesced bulk store + A-frags to regs
                #pragma unroll 1
                for (int i = 0; i < 16; ++i) {
                    int v = i*64 + lane;
                    int row = v >> 5, col = (v & 31) * 4;
                    short4v s = *(const short4v*)&aw[row*136 + col];
                    f32x4 f = { bf2f(s[0]), bf2f(s[1]), bf2f(s[2]), bf2f(s[3]) };
                    *(f32x4*)&out[HOFF + (size_t)(R + row)*128 + col] = f;
                }
                #pragma unroll
                for (int rt = 0; rt < 2; ++rt)
                    #pragma unroll
                    for (int kt = 0; kt < 4; ++kt)
                        hfa[rt][kt] = *(const short8*)&aw[(rt*16 + lo)*136 + kt*32 + hi*8];
            }
            if (u == 20) {                         // t1 A-frags to regs (frees act buffer)
                #pragma unroll
                for (int rt = 0; rt < 2; ++rt)
                    #pragma unroll
                    for (int kt = 0; kt < 4; ++kt)
                        ta[rt][kt] = *(const short8*)&aw[(rt*16 + lo)*136 + kt*32 + hi*8];
            }

            if (u < 20) {                          // ns1: t1 = relu(h @ ns_W1^T + b)
                const int uh = u - 16;
                #pragma unroll
                for (int sub = 0; sub < 2; ++sub) {
                    const int j0 = (uh*2 + sub) * 16;
                    float b1 = ns_b1[j0 + lo];
                    f32x4 a0 = zz4, a1 = zz4;
                    #pragma unroll
                    for (int kt = 0; kt < 4; ++kt) {
                        short8 B = *(const short8*)&smem[halfB + (sub*16 + lo)*136 + kt*32 + hi*8];
                        a0 = MFMA(hfa[0][kt], B, a0);
                        a1 = MFMA(hfa[1][kt], B, a1);
                    }
                    #pragma unroll
                    for (int e = 0; e < 4; ++e) {
                        aw[(4*hi + e)*136 + j0 + lo]      = f2bf(fmaxf(a0[e] + b1, 0.f));
                        aw[(16 + 4*hi + e)*136 + j0 + lo] = f2bf(fmaxf(a1[e] + b1, 0.f));
                    }
                }
            } else if (u < 22) {                   // ns2: z_next = t1 @ ns_W2^T + b  (staged [32][72])
                const int uh = u - 20;
                #pragma unroll
                for (int sub = 0; sub < 2; ++sub) {
                    const int j0 = (uh*2 + sub) * 16;
                    float b2 = ns_b2[j0 + lo];
                    f32x4 a0 = zz4, a1 = zz4;
                    #pragma unroll
                    for (int kt = 0; kt < 4; ++kt) {
                        short8 B = *(const short8*)&smem[halfB + (sub*16 + lo)*136 + kt*32 + hi*8];
                        a0 = MFMA(ta[0][kt], B, a0);
                        a1 = MFMA(ta[1][kt], B, a1);
                    }
                    #pragma unroll
                    for (int e = 0; e < 4; ++e) {
                        aw[(4*hi + e)*72 + j0 + lo]      = f2bf(a0[e] + b2);
                        aw[(16 + 4*hi + e)*72 + j0 + lo] = f2bf(a1[e] + b2);
                    }
                }
                if (u == 21) {                     // coalesced z_next store
                    #pragma unroll 1
                    for (int i = 0; i < 8; ++i) {
                        int v = i*64 + lane;
                        int row = v >> 4, col = (v & 15) * 4;
                        short4v s = *(const short4v*)&aw[row*72 + col];
                        f32x4 f = { bf2f(s[0]), bf2f(s[1]), bf2f(s[2]), bf2f(s[3]) };
                        *(f32x4*)&out[(size_t)(R + row)*64 + col] = f;
                    }
                }
            } else if (u < 24) {                   // rw1: t2r -> cols 0..63
                const int uh = u - 22;
                #pragma unroll
                for (int sub = 0; sub < 2; ++sub) {
                    const int j0 = (uh*2 + sub) * 16;
                    float b1 = rw_b1[j0 + lo];
                    f32x4 a0 = zz4, a1 = zz4;
                    #pragma unroll
                    for (int kt = 0; kt < 4; ++kt) {
                        short8 B = *(const short8*)&smem[halfB + (sub*16 + lo)*136 + kt*32 + hi*8];
                        a0 = MFMA(hfa[0][kt], B, a0);
                        a1 = MFMA(hfa[1][kt], B, a1);
                    }
                    #pragma unroll
                    for (int e = 0; e < 4; ++e) {
                        aw[(4*hi + e)*136 + j0 + lo]      = f2bf(fmaxf(a0[e] + b1, 0.f));
                        aw[(16 + 4*hi + e)*136 + j0 + lo] = f2bf(fmaxf(a1[e] + b1, 0.f));
                    }
                }
            } else {                               // dn1: t2d -> cols 64..127
                const int uh = u - 24;
                #pragma unroll
                for (int sub = 0; sub < 2; ++sub) {
                    const int j0 = (uh*2 + sub) * 16;
                    float b1 = dn_b1[j0 + lo];
                    f32x4 a0 = zz4, a1 = zz4;
                    #pragma unroll
                    for (int kt = 0; kt < 4; ++kt) {
                        short8 B = *(const short8*)&smem[halfB + (sub*16 + lo)*136 + kt*32 + hi*8];
                        a0 = MFMA(hfa[0][kt], B, a0);
                        a1 = MFMA(hfa[1][kt], B, a1);
                    }
                    #pragma unroll
                    for (int e = 0; e < 4; ++e) {
                        aw[(4*hi + e)*136 + 64 + j0 + lo]      = f2bf(fmaxf(a0[e] + b1, 0.f));
                        aw[(16 + 4*hi + e)*136 + 64 + j0 + lo] = f2bf(fmaxf(a1[e] + b1, 0.f));
                    }
                }
            }
        }

        if (u < 25) {
            const int un = u + 1;
            short* dst = &smem[(un & 1) * 6656];
            const int nch = (un < 16) ? 832 : 576;
            stage_commit(dst, nch, t, st);
        }
        __syncthreads();
    }

    // ---- final 1-wide heads: lanes 0..31 reward, 32..63 done ----
    {
        const float* W2   = (lane < 32) ? rw_W2 : dn_W2;
        float acc         = (lane < 32) ? rw_b2[0] : dn_b2[0];
        const int colbase = (lane < 32) ? 0 : 64;
        const int rr      = lane & 31;
        #pragma unroll
        for (int k = 0; k < 64; k += 4) {
            short4v s = *(const short4v*)&aw[rr*136 + colbase + k];
            f32x4 wv  = *(const f32x4*)&W2[k];
            acc += bf2f(s[0])*wv[0] + bf2f(s[1])*wv[1] + bf2f(s[2])*wv[2] + bf2f(s[3])*wv[3];
        }
        size_t ooff = (lane < 32) ? ((size_t)BATCH*64) : ((size_t)BATCH*65);
        out[ooff + R + rr] = acc;
    }
}

extern "C" void kernel_launch(void* const* d_in, const int* in_sizes, int n_in,
                              void* d_out, int out_size, void* d_ws, size_t ws_size,
                              hipStream_t stream) {
    const float* z_t    = (const float*)d_in[0];
    const int*   action = (const int*)  d_in[1];
    const float* hidden = (const float*)d_in[2];
    const float* embed  = (const float*)d_in[3];
    const float* fuse_W = (const float*)d_in[4];
    const float* fuse_b = (const float*)d_in[5];
    const float* W_ih   = (const float*)d_in[6];
    const float* W_hh   = (const float*)d_in[7];
    const float* b_ih   = (const float*)d_in[8];
    const float* b_hh   = (const float*)d_in[9];
    const float* ns_W1  = (const float*)d_in[10];
    const float* ns_b1  = (const float*)d_in[11];
    const float* ns_W2  = (const float*)d_in[12];
    const float* ns_b2  = (const float*)d_in[13];
    const float* rw_W1  = (const float*)d_in[14];
    const float* rw_b1  = (const float*)d_in[15];
    const float* rw_W2  = (const float*)d_in[16];
    const float* rw_b2  = (const float*)d_in[17];
    const float* dn_W1  = (const float*)d_in[18];
    const float* dn_b1  = (const float*)d_in[19];
    const float* dn_W2  = (const float*)d_in[20];
    const float* dn_b2  = (const float*)d_in[21];
    float* out = (float*)d_out;
    short* ws  = (short*)d_ws;

    hipLaunchKernelGGL(prep_weights, dim3((WS_ELEMS + 255) / 256), dim3(256), 0, stream,
                       fuse_W, W_ih, W_hh, ns_W1, ns_W2, rw_W1, dn_W1, ws);

    hipLaunchKernelGGL(gru_mfma, dim3(BATCH / 128), dim3(256), 0, stream,
                       z_t, action, hidden, embed,
                       fuse_b, b_ih, b_hh, ns_b1, ns_b2,
                       rw_b1, rw_W2, rw_b2, dn_b1, dn_W2, dn_b2,
                       ws, out);
}

// Round 3
// 92.993 us; speedup vs baseline: 17.6019x; 2.7449x over previous
//
#include <hip/hip_runtime.h>
#include <cstddef>
#include <cstdint>

#define BATCH 131072
#define HOFF ((size_t)BATCH * 66)

typedef __attribute__((ext_vector_type(8))) short short8;
typedef __attribute__((ext_vector_type(4))) short short4v;
typedef __attribute__((ext_vector_type(4))) float f32x4;

typedef const __attribute__((address_space(1))) unsigned int* gas_t;
typedef __attribute__((address_space(3))) unsigned int* las_t;

// d_ws layout (bf16 elems): fuse [128][104] | 16 GRU units (48 rows x 136, padded to 6656)
//                           | 10 head units (32 rows x 136, padded to 4608)
#define WS_WF    0
#define WS_GRU   13312
#define WS_HEAD  119808
#define WS_ELEMS 165888

#define MFMA(a,b,c) __builtin_amdgcn_mfma_f32_16x16x32_bf16((a),(b),(c),0,0,0)

__device__ __forceinline__ short f2bf(float x) {
    unsigned u = __builtin_bit_cast(unsigned, x);
    unsigned r = (u + 0x7fffu + ((u >> 16) & 1u)) >> 16;   // RNE
    return (short)r;
}
__device__ __forceinline__ float bf2f(short s) {
    unsigned u = ((unsigned)(unsigned short)s) << 16;
    return __builtin_bit_cast(float, u);
}
__device__ __forceinline__ float fsigmoid(float x) { return __builtin_amdgcn_rcpf(1.0f + __expf(-x)); }
__device__ __forceinline__ float ftanh(float x)    { return 1.0f - 2.0f * __builtin_amdgcn_rcpf(1.0f + __expf(2.0f * x)); }

__device__ __forceinline__ short8 packbf(f32x4 a, f32x4 b) {
    short8 r;
    r[0]=f2bf(a[0]); r[1]=f2bf(a[1]); r[2]=f2bf(a[2]); r[3]=f2bf(a[3]);
    r[4]=f2bf(b[0]); r[5]=f2bf(b[1]); r[6]=f2bf(b[2]); r[7]=f2bf(b[3]);
    return r;
}

// async global->LDS staging: linear dest, 16B/lane; NCH always a multiple of 64
// so the tail-pass guard is wave-uniform.
template<int NCH>
__device__ __forceinline__ void stage_lds(const short* __restrict__ src, short* dst, int t) {
    constexpr int NP = (NCH + 255) / 256;
    #pragma unroll
    for (int k = 0; k < NP; ++k) {
        int c = t + 256 * k;
        if ((NCH % 256 == 0) || c < NCH)
            __builtin_amdgcn_global_load_lds((gas_t)(const void*)(src + (size_t)c * 8),
                                             (las_t)(void*)(dst + (size_t)c * 8), 16, 0, 0);
    }
}

// ---------------- prep: f32 weights -> bf16 units in d_ws ----------------
extern "C" __global__ void prep_weights(const float* __restrict__ fuse_W,
                                        const float* __restrict__ W_ih, const float* __restrict__ W_hh,
                                        const float* __restrict__ ns_W1, const float* __restrict__ ns_W2,
                                        const float* __restrict__ rw_W1, const float* __restrict__ dn_W1,
                                        short* __restrict__ ws) {
    int i = blockIdx.x * 256 + threadIdx.x;
    if (i >= WS_ELEMS) return;
    float v = 0.f;
    if (i < WS_GRU) {                       // fuse: [128][104], K padded 80->104
        int j = i / 104, k = i % 104;
        if (k < 80) v = fuse_W[j*80 + k];
    } else if (i < WS_HEAD) {               // GRU units: j = u>>1, part = u&1 (ih/hh), rows gate*16+rr
        int g = (i - WS_GRU) / 6656, e = (i - WS_GRU) % 6656;
        int r = e / 136, k = e % 136;
        if (r < 48 && k < 128) {
            int j = g >> 1;
            const float* W = (g & 1) ? W_hh : W_ih;
            int gate = r >> 4, rr = r & 15;
            v = W[(size_t)(gate*128 + j*16 + rr)*128 + k];
        }
    } else {                                // head units: 0-3 ns_W1, 4-5 ns_W2, 6-7 rw_W1, 8-9 dn_W1
        int h = (i - WS_HEAD) / 4608, e = (i - WS_HEAD) % 4608;
        int r = e / 136, k = e % 136;
        if (r < 32 && k < 128) {
            const float* W; int rb;
            if (h < 4)      { W = ns_W1; rb = h*32; }
            else if (h < 6) { W = ns_W2; rb = (h-4)*32; }
            else if (h < 8) { W = rw_W1; rb = (h-6)*32; }
            else            { W = dn_W1; rb = (h-8)*32; }
            v = W[(size_t)(rb + r)*128 + k];
        }
    }
    ws[i] = f2bf(v);
}

// ---------------- main fused kernel ----------------
extern "C" __global__ __launch_bounds__(256, 2)
void gru_mfma(const float* __restrict__ z_t, const int* __restrict__ action,
              const float* __restrict__ hidden, const float* __restrict__ embed,
              const float* __restrict__ fuse_b,
              const float* __restrict__ b_ih, const float* __restrict__ b_hh,
              const float* __restrict__ ns_b1, const float* __restrict__ ns_b2,
              const float* __restrict__ rw_b1, const float* __restrict__ rw_W2, const float* __restrict__ rw_b2,
              const float* __restrict__ dn_b1, const float* __restrict__ dn_W2, const float* __restrict__ dn_b2,
              const short* __restrict__ ws, float* __restrict__ out)
{
    // [0,13312): weight double-buffer (2 x 6656 shorts). [13312,30720): 4 x 4352 per-wave act buffers.
    __shared__ __align__(16) short smem[30720];   // 61440 B -> 2 blocks/CU

    const int t    = threadIdx.x;
    const int lane = t & 63;
    const int w    = t >> 6;
    const int lo   = lane & 15;
    const int hi   = lane >> 4;
    const int R    = blockIdx.x * 128 + w * 32;   // wave's first batch row
    short* const aw = &smem[13312 + w * 4352];    // act buffer, row stride 136 shorts

    const f32x4 zz4 = {0.f, 0.f, 0.f, 0.f};

    // ---- issue fuse-weight loads into the whole dbuf region (async; drained at barrier) ----
    stage_lds<1664>(ws, &smem[0], t);

    // ---- A-fragments direct from global (row-major == A layout), f32 -> bf16 ----
    short8 fa[2][3];   // fused input, K=96 (z_t 0..63 | emb 64..79 | zero 80..95)
    short8 ha[2][4];   // h0, K=128
    #pragma unroll
    for (int rt = 0; rt < 2; ++rt) {
        const int row = R + rt*16 + lo;
        #pragma unroll
        for (int kt = 0; kt < 2; ++kt) {
            f32x4 p0 = *(const f32x4*)&z_t[(size_t)row*64 + kt*32 + hi*8];
            f32x4 p1 = *(const f32x4*)&z_t[(size_t)row*64 + kt*32 + hi*8 + 4];
            fa[rt][kt] = packbf(p0, p1);
        }
        if (hi < 2) {
            int a = action[row];
            f32x4 e0 = *(const f32x4*)&embed[a*16 + hi*8];
            f32x4 e1 = *(const f32x4*)&embed[a*16 + hi*8 + 4];
            fa[rt][2] = packbf(e0, e1);
        } else {
            short8 z8 = {0,0,0,0,0,0,0,0};
            fa[rt][2] = z8;
        }
        #pragma unroll
        for (int kt = 0; kt < 4; ++kt) {
            f32x4 p0 = *(const f32x4*)&hidden[(size_t)row*128 + kt*32 + hi*8];
            f32x4 p1 = *(const f32x4*)&hidden[(size_t)row*128 + kt*32 + hi*8 + 4];
            ha[rt][kt] = packbf(p0, p1);
        }
    }

    // ---- h0 D-layout transpose through the (free) act buffer; packed bf16 regs ----
    #pragma unroll
    for (int rt = 0; rt < 2; ++rt)
        #pragma unroll
        for (int kt = 0; kt < 4; ++kt)
            *(short8*)&aw[(rt*16 + lo)*136 + kt*32 + hi*8] = ha[rt][kt];
    unsigned h0d[8][2][2];                // [j][rt][e-pair]: lo16 = e=2p, hi16 = e=2p+1
    #pragma unroll
    for (int j = 0; j < 8; ++j)
        #pragma unroll
        for (int rt = 0; rt < 2; ++rt)
            #pragma unroll
            for (int p = 0; p < 2; ++p) {
                unsigned a = (unsigned short)aw[(rt*16 + 4*hi + 2*p    )*136 + j*16 + lo];
                unsigned b = (unsigned short)aw[(rt*16 + 4*hi + 2*p + 1)*136 + j*16 + lo];
                h0d[j][rt][p] = a | (b << 16);
            }
    __syncthreads();   // drains fuse-weight loads (vmcnt) and transpose reads (lgkm)

    // ---- fuse: x = relu(F @ fuse_W^T + b) ----
    #pragma unroll 1
    for (int ct = 0; ct < 8; ++ct) {
        float fb = fuse_b[ct*16 + lo];
        f32x4 a0 = zz4, a1 = zz4;
        #pragma unroll
        for (int kt = 0; kt < 3; ++kt) {
            short8 B = *(const short8*)&smem[(ct*16 + lo)*104 + kt*32 + hi*8];
            a0 = MFMA(fa[0][kt], B, a0);
            a1 = MFMA(fa[1][kt], B, a1);
        }
        #pragma unroll
        for (int e = 0; e < 4; ++e) {
            aw[(4*hi + e)*136 + ct*16 + lo]        = f2bf(fmaxf(a0[e] + fb, 0.f));
            aw[(16 + 4*hi + e)*136 + ct*16 + lo]   = f2bf(fmaxf(a1[e] + fb, 0.f));
        }
    }
    // x A-frags (own wave's LDS; lgkmcnt orders)
    short8 xa[2][4];
    #pragma unroll
    for (int rt = 0; rt < 2; ++rt)
        #pragma unroll
        for (int kt = 0; kt < 4; ++kt)
            xa[rt][kt] = *(const short8*)&aw[(rt*16 + lo)*136 + kt*32 + hi*8];

    __syncthreads();                      // all waves done reading fuse weights
    stage_lds<832>(ws + WS_GRU, &smem[0], t);   // unit 0 -> half 0
    __syncthreads();                      // drain unit-0 loads

    // ---- GRU: fully unrolled, 2 units (ih, hh+elementwise) per j ----
    f32x4 accI[3][2], accH[3][2];
    #pragma unroll
    for (int j = 0; j < 8; ++j) {
        // phase A (unit 2j, half 0): stage unit 2j+1 -> half 1; gi = x @ W_ih^T
        stage_lds<832>(ws + WS_GRU + (size_t)(2*j + 1) * 6656, &smem[6656], t);
        #pragma unroll
        for (int g = 0; g < 3; ++g) {
            accI[g][0] = zz4; accI[g][1] = zz4;
            #pragma unroll
            for (int kt = 0; kt < 4; ++kt) {
                short8 B = *(const short8*)&smem[(g*16 + lo)*136 + kt*32 + hi*8];
                accI[g][0] = MFMA(xa[0][kt], B, accI[g][0]);
                accI[g][1] = MFMA(xa[1][kt], B, accI[g][1]);
            }
        }
        __syncthreads();

        // phase B (unit 2j+1, half 1): stage next -> half 0; gh = h0 @ W_hh^T + elementwise
        if (j < 7) stage_lds<832>(ws + WS_GRU + (size_t)(2*j + 2) * 6656, &smem[0], t);
        else       stage_lds<576>(ws + WS_HEAD, &smem[0], t);
        #pragma unroll
        for (int g = 0; g < 3; ++g) {
            accH[g][0] = zz4; accH[g][1] = zz4;
            #pragma unroll
            for (int kt = 0; kt < 4; ++kt) {
                short8 B = *(const short8*)&smem[6656 + (g*16 + lo)*136 + kt*32 + hi*8];
                accH[g][0] = MFMA(ha[0][kt], B, accH[g][0]);
                accH[g][1] = MFMA(ha[1][kt], B, accH[g][1]);
            }
        }
        {
            const int j0 = j * 16;
            const float bir = b_ih[j0+lo], biz = b_ih[128+j0+lo], bin = b_ih[256+j0+lo];
            const float bhr = b_hh[j0+lo], bhz = b_hh[128+j0+lo], bhn = b_hh[256+j0+lo];
            #pragma unroll
            for (int rt = 0; rt < 2; ++rt) {
                #pragma unroll
                for (int p = 0; p < 2; ++p) {
                    unsigned hp = h0d[j][rt][p];
                    float h0a = bf2f((short)(hp & 0xffffu));
                    float h0b = bf2f((short)(hp >> 16));
                    int e = 2*p;
                    {
                        float rg = fsigmoid(accI[0][rt][e] + bir + accH[0][rt][e] + bhr);
                        float zg = fsigmoid(accI[1][rt][e] + biz + accH[1][rt][e] + bhz);
                        float ng = ftanh(accI[2][rt][e] + bin + rg*(accH[2][rt][e] + bhn));
                        aw[(rt*16 + 4*hi + e)*136 + j0 + lo] = f2bf((1.f - zg)*ng + zg*h0a);
                    }
                    {
                        float rg = fsigmoid(accI[0][rt][e+1] + bir + accH[0][rt][e+1] + bhr);
                        float zg = fsigmoid(accI[1][rt][e+1] + biz + accH[1][rt][e+1] + bhz);
                        float ng = ftanh(accI[2][rt][e+1] + bin + rg*(accH[2][rt][e+1] + bhn));
                        aw[(rt*16 + 4*hi + e+1)*136 + j0 + lo] = f2bf((1.f - zg)*ng + zg*h0b);
                    }
                }
            }
        }
        __syncthreads();
    }

    // ---- heads: units 16..25 (16-19 ns1, 20-21 ns2, 22-23 rw1, 24-25 dn1) ----
    short8 hfa[2][4], ta[2][4];
    #pragma unroll 1
    for (int u = 16; u < 26; ++u) {
        if (u < 25)
            stage_lds<576>(ws + WS_HEAD + (size_t)(u - 15) * 4608, &smem[((u+1)&1)*6656], t);
        const int halfB = (u & 1) * 6656;

        if (u == 16) {                         // h_new: coalesced bulk store + A-frags to regs
            #pragma unroll 1
            for (int i = 0; i < 16; ++i) {
                int v = i*64 + lane;
                int row = v >> 5, col = (v & 31) * 4;
                short4v s = *(const short4v*)&aw[row*136 + col];
                f32x4 f = { bf2f(s[0]), bf2f(s[1]), bf2f(s[2]), bf2f(s[3]) };
                *(f32x4*)&out[HOFF + (size_t)(R + row)*128 + col] = f;
            }
            #pragma unroll
            for (int rt = 0; rt < 2; ++rt)
                #pragma unroll
                for (int kt = 0; kt < 4; ++kt)
                    hfa[rt][kt] = *(const short8*)&aw[(rt*16 + lo)*136 + kt*32 + hi*8];
        }
        if (u == 20) {                         // t1 A-frags to regs
            #pragma unroll
            for (int rt = 0; rt < 2; ++rt)
                #pragma unroll
                for (int kt = 0; kt < 4; ++kt)
                    ta[rt][kt] = *(const short8*)&aw[(rt*16 + lo)*136 + kt*32 + hi*8];
        }

        if (u < 20) {                          // ns1: t1 = relu(h @ ns_W1^T + b)
            const int uh = u - 16;
            #pragma unroll
            for (int sub = 0; sub < 2; ++sub) {
                const int j0 = (uh*2 + sub) * 16;
                float b1 = ns_b1[j0 + lo];
                f32x4 a0 = zz4, a1 = zz4;
                #pragma unroll
                for (int kt = 0; kt < 4; ++kt) {
                    short8 B = *(const short8*)&smem[halfB + (sub*16 + lo)*136 + kt*32 + hi*8];
                    a0 = MFMA(hfa[0][kt], B, a0);
                    a1 = MFMA(hfa[1][kt], B, a1);
                }
                #pragma unroll
                for (int e = 0; e < 4; ++e) {
                    aw[(4*hi + e)*136 + j0 + lo]      = f2bf(fmaxf(a0[e] + b1, 0.f));
                    aw[(16 + 4*hi + e)*136 + j0 + lo] = f2bf(fmaxf(a1[e] + b1, 0.f));
                }
            }
        } else if (u < 22) {                   // ns2: z_next = t1 @ ns_W2^T + b (staged [32][72])
            const int uh = u - 20;
            #pragma unroll
            for (int sub = 0; sub < 2; ++sub) {
                const int j0 = (uh*2 + sub) * 16;
                float b2 = ns_b2[j0 + lo];
                f32x4 a0 = zz4, a1 = zz4;
                #pragma unroll
                for (int kt = 0; kt < 4; ++kt) {
                    short8 B = *(const short8*)&smem[halfB + (sub*16 + lo)*136 + kt*32 + hi*8];
                    a0 = MFMA(ta[0][kt], B, a0);
                    a1 = MFMA(ta[1][kt], B, a1);
                }
                #pragma unroll
                for (int e = 0; e < 4; ++e) {
                    aw[(4*hi + e)*72 + j0 + lo]      = f2bf(a0[e] + b2);
                    aw[(16 + 4*hi + e)*72 + j0 + lo] = f2bf(a1[e] + b2);
                }
            }
            if (u == 21) {                     // coalesced z_next store
                #pragma unroll 1
                for (int i = 0; i < 8; ++i) {
                    int v = i*64 + lane;
                    int row = v >> 4, col = (v & 15) * 4;
                    short4v s = *(const short4v*)&aw[row*72 + col];
                    f32x4 f = { bf2f(s[0]), bf2f(s[1]), bf2f(s[2]), bf2f(s[3]) };
                    *(f32x4*)&out[(size_t)(R + row)*64 + col] = f;
                }
            }
        } else if (u < 24) {                   // rw1: t2r -> cols 0..63
            const int uh = u - 22;
            #pragma unroll
            for (int sub = 0; sub < 2; ++sub) {
                const int j0 = (uh*2 + sub) * 16;
                float b1 = rw_b1[j0 + lo];
                f32x4 a0 = zz4, a1 = zz4;
                #pragma unroll
                for (int kt = 0; kt < 4; ++kt) {
                    short8 B = *(const short8*)&smem[halfB + (sub*16 + lo)*136 + kt*32 + hi*8];
                    a0 = MFMA(hfa[0][kt], B, a0);
                    a1 = MFMA(hfa[1][kt], B, a1);
                }
                #pragma unroll
                for (int e = 0; e < 4; ++e) {
                    aw[(4*hi + e)*136 + j0 + lo]      = f2bf(fmaxf(a0[e] + b1, 0.f));
                    aw[(16 + 4*hi + e)*136 + j0 + lo] = f2bf(fmaxf(a1[e] + b1, 0.f));
                }
            }
        } else {                               // dn1: t2d -> cols 64..127
            const int uh = u - 24;
            #pragma unroll
            for (int sub = 0; sub < 2; ++sub) {
                const int j0 = (uh*2 + sub) * 16;
                float b1 = dn_b1[j0 + lo];
                f32x4 a0 = zz4, a1 = zz4;
                #pragma unroll
                for (int kt = 0; kt < 4; ++kt) {
                    short8 B = *(const short8*)&smem[halfB + (sub*16 + lo)*136 + kt*32 + hi*8];
                    a0 = MFMA(hfa[0][kt], B, a0);
                    a1 = MFMA(hfa[1][kt], B, a1);
                }
                #pragma unroll
                for (int e = 0; e < 4; ++e) {
                    aw[(4*hi + e)*136 + 64 + j0 + lo]      = f2bf(fmaxf(a0[e] + b1, 0.f));
                    aw[(16 + 4*hi + e)*136 + 64 + j0 + lo] = f2bf(fmaxf(a1[e] + b1, 0.f));
                }
            }
        }
        __syncthreads();
    }

    // ---- final 1-wide heads: lanes 0..31 reward, 32..63 done ----
    {
        const float* W2   = (lane < 32) ? rw_W2 : dn_W2;
        float acc         = (lane < 32) ? rw_b2[0] : dn_b2[0];
        const int colbase = (lane < 32) ? 0 : 64;
        const int rr      = lane & 31;
        #pragma unroll
        for (int k = 0; k < 64; k += 4) {
            short4v s = *(const short4v*)&aw[rr*136 + colbase + k];
            f32x4 wv  = *(const f32x4*)&W2[k];
            acc += bf2f(s[0])*wv[0] + bf2f(s[1])*wv[1] + bf2f(s[2])*wv[2] + bf2f(s[3])*wv[3];
        }
        size_t ooff = (lane < 32) ? ((size_t)BATCH*64) : ((size_t)BATCH*65);
        out[ooff + R + rr] = acc;
    }
}

extern "C" void kernel_launch(void* const* d_in, const int* in_sizes, int n_in,
                              void* d_out, int out_size, void* d_ws, size_t ws_size,
                              hipStream_t stream) {
    const float* z_t    = (const float*)d_in[0];
    const int*   action = (const int*)  d_in[1];
    const float* hidden = (const float*)d_in[2];
    const float* embed  = (const float*)d_in[3];
    const float* fuse_W = (const float*)d_in[4];
    const float* fuse_b = (const float*)d_in[5];
    const float* W_ih   = (const float*)d_in[6];
    const float* W_hh   = (const float*)d_in[7];
    const float* b_ih   = (const float*)d_in[8];
    const float* b_hh   = (const float*)d_in[9];
    const float* ns_W1  = (const float*)d_in[10];
    const float* ns_b1  = (const float*)d_in[11];
    const float* ns_W2  = (const float*)d_in[12];
    const float* ns_b2  = (const float*)d_in[13];
    const float* rw_W1  = (const float*)d_in[14];
    const float* rw_b1  = (const float*)d_in[15];
    const float* rw_W2  = (const float*)d_in[16];
    const float* rw_b2  = (const float*)d_in[17];
    const float* dn_W1  = (const float*)d_in[18];
    const float* dn_b1  = (const float*)d_in[19];
    const float* dn_W2  = (const float*)d_in[20];
    const float* dn_b2  = (const float*)d_in[21];
    float* out = (float*)d_out;
    short* ws  = (short*)d_ws;

    hipLaunchKernelGGL(prep_weights, dim3((WS_ELEMS + 255) / 256), dim3(256), 0, stream,
                       fuse_W, W_ih, W_hh, ns_W1, ns_W2, rw_W1, dn_W1, ws);

    hipLaunchKernelGGL(gru_mfma, dim3(BATCH / 128), dim3(256), 0, stream,
                       z_t, action, hidden, embed,
                       fuse_b, b_ih, b_hh, ns_b1, ns_b2,
                       rw_b1, rw_W2, rw_b2, dn_b1, dn_W2, dn_b2,
                       ws, out);
}